// Round 2
// 427.419 us; speedup vs baseline: 1.0392x; 1.0392x over previous
//
#include <hip/hip_runtime.h>

// GAT self-attention: Wh = h@W; out = softmax(leaky_relu(Wh@Wh^T)) @ Wh
// N=8192, IN_F=256, OUT_F=128. adj input unused by the math.
//
// Round 2: revert to the PROVEN LDS layouts (K [64][136], Vt [128][72], P
// scratch, all plain C++ DS ops — no tr-read, no raw-address asm). Keep the
// verifiable structural wins: T14 reg-held prefetch (issue tile it+1's global
// loads before tile it's compute; ds_write after the post-compute barrier ->
// global latency hidden under compute), NSPLIT=6 -> 768 blocks = 3 blocks/CU
// (launch_bounds(256,3), LDS 45KB -> 135KB/CU), T13 defer-max, T5 setprio,
// float4 combine.

#define SEQ   8192
#define DIM   128
#define IN_F  256
#define BM    64
#define BN    64
#define NSPLIT 6
#define NKT   (SEQ / BN)      // 128 key tiles total

typedef __attribute__((ext_vector_type(8))) _Float16 f16x8;
typedef __attribute__((ext_vector_type(4))) _Float16 f16x4;
typedef __attribute__((ext_vector_type(4))) float   floatx4;

// ---------------------------------------------------------------------------
// Kernel 1: Wh = h @ W (fp32 accum), emit Wh (f16, row-major) and Wh^T (f16)
// block = 256 threads = 8 rows x 32 col-groups(float4). 1024 blocks.
// ---------------------------------------------------------------------------
__global__ __launch_bounds__(256) void wh_kernel(
    const float* __restrict__ h, const float* __restrict__ W,
    _Float16* __restrict__ Wh16, _Float16* __restrict__ WhT16) {
  int tid = threadIdx.x;
  int cg  = tid & 31;         // column group: 4 fp32 cols
  int rl  = tid >> 5;         // 0..7
  int row = blockIdx.x * 8 + rl;
  const float4* W4 = (const float4*)W;          // [256][32] of float4
  const float4* h4 = (const float4*)(h + (size_t)row * IN_F);
  float4 acc = make_float4(0.f, 0.f, 0.f, 0.f);
#pragma unroll 8
  for (int k4 = 0; k4 < IN_F / 4; k4++) {
    float4 hv = h4[k4];
    float4 w0 = W4[(k4 * 4 + 0) * 32 + cg];
    float4 w1 = W4[(k4 * 4 + 1) * 32 + cg];
    float4 w2 = W4[(k4 * 4 + 2) * 32 + cg];
    float4 w3 = W4[(k4 * 4 + 3) * 32 + cg];
    acc.x += hv.x * w0.x + hv.y * w1.x + hv.z * w2.x + hv.w * w3.x;
    acc.y += hv.x * w0.y + hv.y * w1.y + hv.z * w2.y + hv.w * w3.y;
    acc.z += hv.x * w0.z + hv.y * w1.z + hv.z * w2.z + hv.w * w3.z;
    acc.w += hv.x * w0.w + hv.y * w1.w + hv.z * w2.w + hv.w * w3.w;
  }
  f16x4 r;
  r[0] = (_Float16)acc.x; r[1] = (_Float16)acc.y;
  r[2] = (_Float16)acc.z; r[3] = (_Float16)acc.w;
  *(f16x4*)&Wh16[(size_t)row * DIM + cg * 4] = r;
#pragma unroll
  for (int j = 0; j < 4; j++)
    WhT16[(size_t)(cg * 4 + j) * SEQ + row] = r[j];
}

// ---------------------------------------------------------------------------
// Kernel 2: flash attention. grid = (128 qtiles, NSPLIT), block = 256 (4 waves)
// wave w owns Q rows [qtile*64 + w*16, +16). Iterate 64-key tiles (21 or 22
// per split). Single-buffered LDS + register-held prefetch of the next tile:
//   top of it: issue global loads for tile it+1 (held in 32 VGPRs)
//   compute tile it from LDS
//   __syncthreads (reads done) -> ds_write tile it+1 -> __syncthreads (ready)
// LDS: Ksh [64][136] + Vtsh [128][72] + Psh [4][16][72] = 22528 halves = 45KB.
// ---------------------------------------------------------------------------
__global__ __launch_bounds__(256, 3) void flash_kernel(
    const _Float16* __restrict__ Wh16, const _Float16* __restrict__ WhT16,
    float* __restrict__ Opart, float* __restrict__ mpart,
    float* __restrict__ lpart) {
  __shared__ _Float16 lds[22528];           // 45056 B
  _Float16* Ksh  = lds;                     // 64*136  = 8704 halves
  _Float16* Vtsh = lds + 8704;              // 128*72  = 9216
  _Float16* Psh  = lds + 8704 + 9216;       // 4*16*72 = 4608

  const int tid  = threadIdx.x;
  const int lane = tid & 63;
  const int wave = tid >> 6;
  const int n16  = lane & 15;
  const int quad = lane >> 4;

  const int qbase  = blockIdx.x * BM + wave * 16;
  const int sp     = blockIdx.y;
  const int tstart = (sp * NKT) / NSPLIT;
  const int tend   = ((sp + 1) * NKT) / NSPLIT;
  const int jbase0 = tstart * BN;
  const int jcount = tend - tstart;          // 21 or 22

  // Q A-fragments, resident for the whole loop: A[m=n16][k=quad*8+j+32c]
  f16x8 qf[4];
#pragma unroll
  for (int c = 0; c < 4; c++)
    qf[c] = *(const f16x8*)&Wh16[(size_t)(qbase + n16) * DIM + c * 32 + quad * 8];

  // staging decomposition (identical coverage to the proven r0 kernel):
  // K: key = rep*16 + (tid>>4), d-chunk = (tid&15)*8
  // Vt: d = rep*32 + (tid>>3), key-chunk = (tid&7)*8
  const int krow = tid >> 4;
  const int kcol = (tid & 15) * 8;
  const int vrow = tid >> 3;
  const int vcol = (tid & 7) * 8;
  f16x8 kreg[4], vreg[4];
  auto stage_load = [&](int jb) {
#pragma unroll
    for (int rep = 0; rep < 4; rep++)
      kreg[rep] = *(const f16x8*)&Wh16[(size_t)(jb + rep * 16 + krow) * DIM + kcol];
#pragma unroll
    for (int rep = 0; rep < 4; rep++)
      vreg[rep] = *(const f16x8*)&WhT16[(size_t)(rep * 32 + vrow) * SEQ + jb + vcol];
  };
  auto stage_write = [&]() {
#pragma unroll
    for (int rep = 0; rep < 4; rep++)
      *(f16x8*)&Ksh[(rep * 16 + krow) * 136 + kcol] = kreg[rep];
#pragma unroll
    for (int rep = 0; rep < 4; rep++)
      *(f16x8*)&Vtsh[(rep * 32 + vrow) * 72 + vcol] = vreg[rep];
  };

  floatx4 o[8];
#pragma unroll
  for (int ct = 0; ct < 8; ct++) o[ct] = (floatx4){0.f, 0.f, 0.f, 0.f};
  float m_run[4], l_run[4];
#pragma unroll
  for (int e = 0; e < 4; e++) { m_run[e] = -1e30f; l_run[e] = 0.f; }

  _Float16* Pw = Psh + wave * 1152;         // 16 rows x 72 halves

  // prologue: tile 0 staged (latency exposed once)
  stage_load(jbase0);
  stage_write();
  __syncthreads();

  for (int it = 0; it < jcount; it++) {
    // T14: issue next tile's global loads now; write them to LDS after the
    // post-compute barrier. Latency hides under this tile's compute.
    if (it + 1 < jcount) stage_load(jbase0 + (it + 1) * BN);

    // ---- S = Q K^T : 4 key-subtiles x 4 k-chunks
    floatx4 s[4];
    __builtin_amdgcn_s_setprio(1);
#pragma unroll
    for (int t = 0; t < 4; t++) {
      s[t] = (floatx4){0.f, 0.f, 0.f, 0.f};
#pragma unroll
      for (int c = 0; c < 4; c++) {
        f16x8 kf = *(const f16x8*)&Ksh[(t * 16 + n16) * 136 + c * 32 + quad * 8];
        s[t] = __builtin_amdgcn_mfma_f32_16x16x32_f16(qf[c], kf, s[t], 0, 0, 0);
      }
    }
    __builtin_amdgcn_s_setprio(0);

    // ---- leaky_relu(0.2)
#pragma unroll
    for (int t = 0; t < 4; t++)
#pragma unroll
      for (int e = 0; e < 4; e++) {
        float v = s[t][e];
        s[t][e] = v > 0.f ? v : 0.2f * v;
      }

    // ---- online softmax: row r = quad*4+e lives in the 16 lanes of `quad`
    float mx[4];
#pragma unroll
    for (int e = 0; e < 4; e++) {
      float v = fmaxf(fmaxf(s[0][e], s[1][e]), fmaxf(s[2][e], s[3][e]));
      v = fmaxf(v, __shfl_xor(v, 1, 64));
      v = fmaxf(v, __shfl_xor(v, 2, 64));
      v = fmaxf(v, __shfl_xor(v, 4, 64));
      v = fmaxf(v, __shfl_xor(v, 8, 64));
      mx[e] = v;
    }
    // T13 defer-max: skip the O/l rescale while tile max <= running max + 8.
    // P is then bounded by e^8 ~ 2981, safely inside f16 range.
    float need = fmaxf(fmaxf(mx[0] - m_run[0], mx[1] - m_run[1]),
                       fmaxf(mx[2] - m_run[2], mx[3] - m_run[3]));
    if (!__all(need <= 8.f)) {
#pragma unroll
      for (int e = 0; e < 4; e++) {
        float mnew = fmaxf(m_run[e], mx[e]);
        float al   = __expf(m_run[e] - mnew);
        m_run[e] = mnew;
        l_run[e] *= al;
#pragma unroll
        for (int ct = 0; ct < 8; ct++) o[ct][e] *= al;
      }
    }
    float rs[4] = {0.f, 0.f, 0.f, 0.f};
#pragma unroll
    for (int t = 0; t < 4; t++)
#pragma unroll
      for (int e = 0; e < 4; e++) {
        float p = __expf(s[t][e] - m_run[e]);
        s[t][e] = p;
        rs[e] += p;
      }
#pragma unroll
    for (int e = 0; e < 4; e++) {
      float v = rs[e];
      v += __shfl_xor(v, 1, 64);
      v += __shfl_xor(v, 2, 64);
      v += __shfl_xor(v, 4, 64);
      v += __shfl_xor(v, 8, 64);
      l_run[e] += v;
    }

    // ---- P: C-layout -> A-layout via per-wave LDS region (intra-wave only;
    // same-wave DS ops complete in order, lgkmcnt(0) kept for safety)
#pragma unroll
    for (int t = 0; t < 4; t++)
#pragma unroll
      for (int e = 0; e < 4; e++)
        Pw[(quad * 4 + e) * 72 + t * 16 + n16] = (_Float16)s[t][e];
    asm volatile("s_waitcnt lgkmcnt(0)" ::: "memory");
    f16x8 pa[2];
#pragma unroll
    for (int c = 0; c < 2; c++)
      pa[c] = *(const f16x8*)&Pw[n16 * 72 + c * 32 + quad * 8];

    // ---- O += P V : 8 col-tiles x 2 key-chunks
    __builtin_amdgcn_s_setprio(1);
#pragma unroll
    for (int ct = 0; ct < 8; ct++)
#pragma unroll
      for (int c = 0; c < 2; c++) {
        f16x8 vf = *(const f16x8*)&Vtsh[(ct * 16 + n16) * 72 + c * 32 + quad * 8];
        o[ct] = __builtin_amdgcn_mfma_f32_16x16x32_f16(pa[c], vf, o[ct], 0, 0, 0);
      }
    __builtin_amdgcn_s_setprio(0);

    __syncthreads();                       // all waves done reading tile it
    if (it + 1 < jcount) {
      stage_write();                       // compiler inserts vmcnt waits here
      __syncthreads();                     // tile it+1 ready
    }
  }

  // ---- write unnormalized partials for this key-split
  float* Op = Opart + (size_t)sp * SEQ * DIM;
#pragma unroll
  for (int ct = 0; ct < 8; ct++)
#pragma unroll
    for (int e = 0; e < 4; e++) {
      int row = qbase + quad * 4 + e;
      Op[(size_t)row * DIM + ct * 16 + n16] = o[ct][e];
    }
  if (n16 == 0) {
#pragma unroll
    for (int e = 0; e < 4; e++) {
      int row = qbase + quad * 4 + e;
      mpart[sp * SEQ + row] = m_run[e];
      lpart[sp * SEQ + row] = l_run[e];
    }
  }
}

// ---------------------------------------------------------------------------
// Kernel 3: log-sum-exp combine of NSPLIT partials -> out fp32 (float4/thread)
// ---------------------------------------------------------------------------
__global__ __launch_bounds__(256) void combine_kernel(
    const float* __restrict__ Opart, const float* __restrict__ mpart,
    const float* __restrict__ lpart, float* __restrict__ out) {
  int idx4 = blockIdx.x * 256 + threadIdx.x;   // 0 .. SEQ*DIM/4-1
  int row  = idx4 >> 5;                        // 32 float4 per row
  float M = -1e30f;
#pragma unroll
  for (int p = 0; p < NSPLIT; p++) M = fmaxf(M, mpart[p * SEQ + row]);
  float den = 0.f;
  float4 num = make_float4(0.f, 0.f, 0.f, 0.f);
#pragma unroll
  for (int p = 0; p < NSPLIT; p++) {
    float e = __expf(mpart[p * SEQ + row] - M);
    den += e * lpart[p * SEQ + row];
    float4 v = ((const float4*)Opart)[(size_t)p * (SEQ * DIM / 4) + idx4];
    num.x += e * v.x; num.y += e * v.y; num.z += e * v.z; num.w += e * v.w;
  }
  float inv = 1.f / den;
  ((float4*)out)[idx4] = make_float4(num.x * inv, num.y * inv,
                                     num.z * inv, num.w * inv);
}

// ---------------------------------------------------------------------------
extern "C" void kernel_launch(void* const* d_in, const int* in_sizes, int n_in,
                              void* d_out, int out_size, void* d_ws,
                              size_t ws_size, hipStream_t stream) {
  const float* h = (const float*)d_in[0];
  // d_in[1] = adj  (unused by the reference math)
  const float* W = (const float*)d_in[2];
  float* out = (float*)d_out;

  char* ws = (char*)d_ws;
  _Float16* Wh16  = (_Float16*)ws;                                 // 2 MiB
  _Float16* WhT16 = (_Float16*)(ws + (size_t)2 * 1024 * 1024);     // 2 MiB
  float* Opart = (float*)(ws + (size_t)4 * 1024 * 1024);           // 24 MiB
  float* mpart = (float*)(ws + (size_t)28 * 1024 * 1024);          // 192 KiB
  float* lpart = (float*)(ws + (size_t)28 * 1024 * 1024 + 256 * 1024);

  wh_kernel<<<SEQ / 8, 256, 0, stream>>>(h, W, Wh16, WhT16);
  dim3 grid(SEQ / BM, NSPLIT);
  flash_kernel<<<grid, 256, 0, stream>>>(Wh16, WhT16, Opart, mpart, lpart);
  combine_kernel<<<(SEQ * DIM / 4) / 256, 256, 0, stream>>>(Opart, mpart, lpart, out);
}

// Round 3
// 407.947 us; speedup vs baseline: 1.0888x; 1.0477x over previous
//
#include <hip/hip_runtime.h>

// GAT self-attention: Wh = h@W; out = softmax(leaky_relu(Wh@Wh^T)) @ Wh
// N=8192, IN_F=256, OUT_F=128. adj input unused by the math.
//
// Round 3: swapped QK^T (S^T = mfma(kf, qf)) makes softmax lane-local:
//   lane (n16,quad) holds S[q=n16][key=16t+quad*4+e]
//   -> max/sum = in-lane tree + 2 shfl_xor (was 32 shfl_xor/tile)
//   -> m/l/alpha per-lane scalars; P write = 4 ds_write_b64 (was 16 b16)
//   -> PV in O^T form: o[ct] = mfma(vf, pb) with IDENTICAL Vtsh reads;
//      epilogue = 8 coalesced float4 stores.
// DS-pipe ops per tile per wave: 82 -> 42. Everything else kept from the
// passing r2 kernel (reg-held prefetch, NSPLIT=6 / 3 blocks/CU, defer-max,
// setprio, float4 combine).

#define SEQ   8192
#define DIM   128
#define IN_F  256
#define BM    64
#define BN    64
#define NSPLIT 6
#define NKT   (SEQ / BN)      // 128 key tiles total

typedef __attribute__((ext_vector_type(8))) _Float16 f16x8;
typedef __attribute__((ext_vector_type(4))) _Float16 f16x4;
typedef __attribute__((ext_vector_type(4))) float   floatx4;

// ---------------------------------------------------------------------------
// Kernel 1: Wh = h @ W (fp32 accum), emit Wh (f16, row-major) and Wh^T (f16)
// ---------------------------------------------------------------------------
__global__ __launch_bounds__(256) void wh_kernel(
    const float* __restrict__ h, const float* __restrict__ W,
    _Float16* __restrict__ Wh16, _Float16* __restrict__ WhT16) {
  int tid = threadIdx.x;
  int cg  = tid & 31;         // column group: 4 fp32 cols
  int rl  = tid >> 5;         // 0..7
  int row = blockIdx.x * 8 + rl;
  const float4* W4 = (const float4*)W;          // [256][32] of float4
  const float4* h4 = (const float4*)(h + (size_t)row * IN_F);
  float4 acc = make_float4(0.f, 0.f, 0.f, 0.f);
#pragma unroll 8
  for (int k4 = 0; k4 < IN_F / 4; k4++) {
    float4 hv = h4[k4];
    float4 w0 = W4[(k4 * 4 + 0) * 32 + cg];
    float4 w1 = W4[(k4 * 4 + 1) * 32 + cg];
    float4 w2 = W4[(k4 * 4 + 2) * 32 + cg];
    float4 w3 = W4[(k4 * 4 + 3) * 32 + cg];
    acc.x += hv.x * w0.x + hv.y * w1.x + hv.z * w2.x + hv.w * w3.x;
    acc.y += hv.x * w0.y + hv.y * w1.y + hv.z * w2.y + hv.w * w3.y;
    acc.z += hv.x * w0.z + hv.y * w1.z + hv.z * w2.z + hv.w * w3.z;
    acc.w += hv.x * w0.w + hv.y * w1.w + hv.z * w2.w + hv.w * w3.w;
  }
  f16x4 r;
  r[0] = (_Float16)acc.x; r[1] = (_Float16)acc.y;
  r[2] = (_Float16)acc.z; r[3] = (_Float16)acc.w;
  *(f16x4*)&Wh16[(size_t)row * DIM + cg * 4] = r;
#pragma unroll
  for (int j = 0; j < 4; j++)
    WhT16[(size_t)(cg * 4 + j) * SEQ + row] = r[j];
}

// ---------------------------------------------------------------------------
// Kernel 2: flash attention, swapped-QK^T form. grid = (128 qtiles, NSPLIT),
// block = 256 (4 waves); wave w owns Q rows [qtile*64 + w*16, +16).
// LDS: Ksh [64][136] + Vtsh [128][72] + Psh [4][16][72] = 22528 halves = 45KB.
// ---------------------------------------------------------------------------
__global__ __launch_bounds__(256, 3) void flash_kernel(
    const _Float16* __restrict__ Wh16, const _Float16* __restrict__ WhT16,
    float* __restrict__ Opart, float* __restrict__ mpart,
    float* __restrict__ lpart) {
  __shared__ _Float16 lds[22528];           // 45056 B
  _Float16* Ksh  = lds;                     // 64*136  = 8704 halves
  _Float16* Vtsh = lds + 8704;              // 128*72  = 9216
  _Float16* Psh  = lds + 8704 + 9216;       // 4*16*72 = 4608

  const int tid  = threadIdx.x;
  const int lane = tid & 63;
  const int wave = tid >> 6;
  const int n16  = lane & 15;
  const int quad = lane >> 4;

  const int qbase  = blockIdx.x * BM + wave * 16;
  const int sp     = blockIdx.y;
  const int tstart = (sp * NKT) / NSPLIT;
  const int tend   = ((sp + 1) * NKT) / NSPLIT;
  const int jbase0 = tstart * BN;
  const int jcount = tend - tstart;          // 21 or 22

  // Q fragments (used as the B operand after the swap; same registers/layout):
  // element map: Q[row = qbase+n16][d = c*32 + quad*8 + j]
  f16x8 qf[4];
#pragma unroll
  for (int c = 0; c < 4; c++)
    qf[c] = *(const f16x8*)&Wh16[(size_t)(qbase + n16) * DIM + c * 32 + quad * 8];

  // staging decomposition (identical to the passing r2 kernel)
  const int krow = tid >> 4;
  const int kcol = (tid & 15) * 8;
  const int vrow = tid >> 3;
  const int vcol = (tid & 7) * 8;
  f16x8 kreg[4], vreg[4];
  auto stage_load = [&](int jb) {
#pragma unroll
    for (int rep = 0; rep < 4; rep++)
      kreg[rep] = *(const f16x8*)&Wh16[(size_t)(jb + rep * 16 + krow) * DIM + kcol];
#pragma unroll
    for (int rep = 0; rep < 4; rep++)
      vreg[rep] = *(const f16x8*)&WhT16[(size_t)(rep * 32 + vrow) * SEQ + jb + vcol];
  };
  auto stage_write = [&]() {
#pragma unroll
    for (int rep = 0; rep < 4; rep++)
      *(f16x8*)&Ksh[(rep * 16 + krow) * 136 + kcol] = kreg[rep];
#pragma unroll
    for (int rep = 0; rep < 4; rep++)
      *(f16x8*)&Vtsh[(rep * 32 + vrow) * 72 + vcol] = vreg[rep];
  };

  // O^T accumulators: o[ct][e] = O[q = n16][d = ct*16 + quad*4 + e]
  floatx4 o[8];
#pragma unroll
  for (int ct = 0; ct < 8; ct++) o[ct] = (floatx4){0.f, 0.f, 0.f, 0.f};
  float m_run = -1e30f, l_run = 0.f;        // per-lane scalars (row q = n16)

  _Float16* Pw = Psh + wave * 1152;         // this wave's 16 x 72 halves

  // prologue: tile 0 staged (latency exposed once)
  stage_load(jbase0);
  stage_write();
  __syncthreads();

  for (int it = 0; it < jcount; it++) {
    // T14: issue next tile's global loads now; ds_write after post-compute
    // barrier. Latency hides under this tile's compute.
    if (it + 1 < jcount) stage_load(jbase0 + (it + 1) * BN);

    // ---- S^T = K Q^T : s[t][e] = S[q=n16][key = t*16 + quad*4 + e]
    floatx4 s[4];
    __builtin_amdgcn_s_setprio(1);
#pragma unroll
    for (int t = 0; t < 4; t++) {
      s[t] = (floatx4){0.f, 0.f, 0.f, 0.f};
#pragma unroll
      for (int c = 0; c < 4; c++) {
        f16x8 kf = *(const f16x8*)&Ksh[(t * 16 + n16) * 136 + c * 32 + quad * 8];
        s[t] = __builtin_amdgcn_mfma_f32_16x16x32_f16(kf, qf[c], s[t], 0, 0, 0);
      }
    }
    __builtin_amdgcn_s_setprio(0);

    // ---- leaky_relu(0.2) + in-lane max over this lane's 16 keys
    float mx = -1e30f;
#pragma unroll
    for (int t = 0; t < 4; t++)
#pragma unroll
      for (int e = 0; e < 4; e++) {
        float v = s[t][e];
        v = v > 0.f ? v : 0.2f * v;
        s[t][e] = v;
        mx = fmaxf(mx, v);
      }
    // row max across the 4 quads holding row q = n16
    mx = fmaxf(mx, __shfl_xor(mx, 16, 64));
    mx = fmaxf(mx, __shfl_xor(mx, 32, 64));

    // T13 defer-max: skip O/l rescale while tile max <= running max + 8.
    // P then bounded by e^8 ~ 2981, inside f16 range.
    if (!__all(mx - m_run <= 8.f)) {
      float mnew = fmaxf(m_run, mx);
      float al   = __expf(m_run - mnew);
      m_run = mnew;
      l_run *= al;
#pragma unroll
      for (int ct = 0; ct < 8; ct++)
#pragma unroll
        for (int e = 0; e < 4; e++) o[ct][e] *= al;
    }

    // ---- P = exp(S - m), in-lane row-sum + 2 shfl
    float rs = 0.f;
#pragma unroll
    for (int t = 0; t < 4; t++)
#pragma unroll
      for (int e = 0; e < 4; e++) {
        float p = __expf(s[t][e] - m_run);
        s[t][e] = p;
        rs += p;
      }
    rs += __shfl_xor(rs, 16, 64);
    rs += __shfl_xor(rs, 32, 64);
    l_run += rs;

    // ---- P -> LDS (row q = n16, keys 16t+quad*4+e are e-contiguous: b64 x4)
#pragma unroll
    for (int t = 0; t < 4; t++) {
      f16x4 pw;
      pw[0] = (_Float16)s[t][0]; pw[1] = (_Float16)s[t][1];
      pw[2] = (_Float16)s[t][2]; pw[3] = (_Float16)s[t][3];
      *(f16x4*)&Pw[n16 * 72 + t * 16 + quad * 4] = pw;
    }
    asm volatile("s_waitcnt lgkmcnt(0)" ::: "memory");
    // B-operand fragments: pb[c] = P[q=n16][key = c*32 + quad*8 + j]
    f16x8 pb[2];
#pragma unroll
    for (int c = 0; c < 2; c++)
      pb[c] = *(const f16x8*)&Pw[n16 * 72 + c * 32 + quad * 8];

    // ---- O^T += V^T P^T : identical Vtsh reads as before, operands swapped
    __builtin_amdgcn_s_setprio(1);
#pragma unroll
    for (int ct = 0; ct < 8; ct++)
#pragma unroll
      for (int c = 0; c < 2; c++) {
        f16x8 vf = *(const f16x8*)&Vtsh[(ct * 16 + n16) * 72 + c * 32 + quad * 8];
        o[ct] = __builtin_amdgcn_mfma_f32_16x16x32_f16(vf, pb[c], o[ct], 0, 0, 0);
      }
    __builtin_amdgcn_s_setprio(0);

    __syncthreads();                       // all waves done reading tile it
    if (it + 1 < jcount) {
      stage_write();                       // compiler inserts vmcnt waits
      __syncthreads();                     // tile it+1 ready
    }
  }

  // ---- write unnormalized partials: lane (n16,quad) owns row qbase+n16,
  // d-range [ct*16 + quad*4, +4) -> coalesced float4 stores
  float* Op = Opart + (size_t)sp * SEQ * DIM;
#pragma unroll
  for (int ct = 0; ct < 8; ct++)
    *(float4*)&Op[(size_t)(qbase + n16) * DIM + ct * 16 + quad * 4] =
        make_float4(o[ct][0], o[ct][1], o[ct][2], o[ct][3]);
  if (quad == 0) {
    mpart[sp * SEQ + qbase + n16] = m_run;
    lpart[sp * SEQ + qbase + n16] = l_run;
  }
}

// ---------------------------------------------------------------------------
// Kernel 3: log-sum-exp combine of NSPLIT partials -> out fp32 (float4/thread)
// ---------------------------------------------------------------------------
__global__ __launch_bounds__(256) void combine_kernel(
    const float* __restrict__ Opart, const float* __restrict__ mpart,
    const float* __restrict__ lpart, float* __restrict__ out) {
  int idx4 = blockIdx.x * 256 + threadIdx.x;   // 0 .. SEQ*DIM/4-1
  int row  = idx4 >> 5;                        // 32 float4 per row
  float M = -1e30f;
#pragma unroll
  for (int p = 0; p < NSPLIT; p++) M = fmaxf(M, mpart[p * SEQ + row]);
  float den = 0.f;
  float4 num = make_float4(0.f, 0.f, 0.f, 0.f);
#pragma unroll
  for (int p = 0; p < NSPLIT; p++) {
    float e = __expf(mpart[p * SEQ + row] - M);
    den += e * lpart[p * SEQ + row];
    float4 v = ((const float4*)Opart)[(size_t)p * (SEQ * DIM / 4) + idx4];
    num.x += e * v.x; num.y += e * v.y; num.z += e * v.z; num.w += e * v.w;
  }
  float inv = 1.f / den;
  ((float4*)out)[idx4] = make_float4(num.x * inv, num.y * inv,
                                     num.z * inv, num.w * inv);
}

// ---------------------------------------------------------------------------
extern "C" void kernel_launch(void* const* d_in, const int* in_sizes, int n_in,
                              void* d_out, int out_size, void* d_ws,
                              size_t ws_size, hipStream_t stream) {
  const float* h = (const float*)d_in[0];
  // d_in[1] = adj  (unused by the reference math)
  const float* W = (const float*)d_in[2];
  float* out = (float*)d_out;

  char* ws = (char*)d_ws;
  _Float16* Wh16  = (_Float16*)ws;                                 // 2 MiB
  _Float16* WhT16 = (_Float16*)(ws + (size_t)2 * 1024 * 1024);     // 2 MiB
  float* Opart = (float*)(ws + (size_t)4 * 1024 * 1024);           // 24 MiB
  float* mpart = (float*)(ws + (size_t)28 * 1024 * 1024);          // 192 KiB
  float* lpart = (float*)(ws + (size_t)28 * 1024 * 1024 + 256 * 1024);

  wh_kernel<<<SEQ / 8, 256, 0, stream>>>(h, W, Wh16, WhT16);
  dim3 grid(SEQ / BM, NSPLIT);
  flash_kernel<<<grid, 256, 0, stream>>>(Wh16, WhT16, Opart, mpart, lpart);
  combine_kernel<<<(SEQ * DIM / 4) / 256, 256, 0, stream>>>(Opart, mpart, lpart, out);
}